// Round 1
// baseline (1622.193 us; speedup 1.0000x reference)
//
#include <hip/hip_runtime.h>
#include <cstdint>
#include <cstddef>

#define H 4
#define DK 128
#define DV 256
#define NH 2
#define HID 1024
#define KSZ 4

__device__ __forceinline__ float wave_sum(float x) {
#pragma unroll
  for (int off = 1; off < 64; off <<= 1) x += __shfl_xor(x, off, 64);
  return x;
}

// ---------------- generic fp32 tiled GEMM: C[M,N] = A[M,K] @ B[K,N], row-major, dims % 64 == 0 (K%16==0)
#define GT 64
#define GTK 16
__global__ __launch_bounds__(256) void gemm_f32(const float* __restrict__ A,
                                                const float* __restrict__ B,
                                                float* __restrict__ C,
                                                int M, int N, int K) {
  __shared__ float As[GTK][GT + 1];
  __shared__ float Bs[GTK][GT + 1];
  const int tid = threadIdx.x;
  const int tx = tid & 15, ty = tid >> 4;
  const int row0 = blockIdx.y * GT, col0 = blockIdx.x * GT;
  float acc[4][4] = {};
  for (int k0 = 0; k0 < K; k0 += GTK) {
#pragma unroll
    for (int i = 0; i < 4; i++) {
      int idx = tid + i * 256;
      int m = idx >> 4, kk = idx & 15;
      As[kk][m] = A[(size_t)(row0 + m) * K + k0 + kk];
      int kb = idx >> 6, n = idx & 63;
      Bs[kb][n] = B[(size_t)(k0 + kb) * N + col0 + n];
    }
    __syncthreads();
#pragma unroll
    for (int kk = 0; kk < GTK; kk++) {
      float a[4], b[4];
#pragma unroll
      for (int i = 0; i < 4; i++) a[i] = As[kk][ty * 4 + i];
#pragma unroll
      for (int j = 0; j < 4; j++) b[j] = Bs[kk][tx * 4 + j];
#pragma unroll
      for (int i = 0; i < 4; i++)
#pragma unroll
        for (int j = 0; j < 4; j++) acc[i][j] = fmaf(a[i], b[j], acc[i][j]);
    }
    __syncthreads();
  }
#pragma unroll
  for (int i = 0; i < 4; i++) {
    size_t r = (size_t)(row0 + ty * 4 + i);
#pragma unroll
    for (int j = 0; j < 4; j++) C[r * N + col0 + tx * 4 + j] = acc[i][j];
  }
}

// ---------------- beta / g tiny projections with fused activations
// beta[row*8 + (i*H+h)] = 2*sigmoid(hs_row . Wb[:, i*H+h])
// g[row*4 + h]          = -exp(A_log[h]) * softplus(hs_row . Wa[:, h] + dt_bias[h])
__global__ __launch_bounds__(256) void proj_bg(const float* __restrict__ hs,
                                               const float* __restrict__ Wb,
                                               const float* __restrict__ Wa,
                                               const float* __restrict__ A_log,
                                               const float* __restrict__ dt_bias,
                                               float* __restrict__ beta,
                                               float* __restrict__ g) {
  int row = blockIdx.x;  // b*T + t
  int lane = threadIdx.x & 63;
  int wave = threadIdx.x >> 6;
  const float* x = hs + (size_t)row * HID;
  for (int out = wave; out < 12; out += 4) {
    float sum = 0.f;
    if (out < 8) {
      for (int k = lane; k < HID; k += 64) sum = fmaf(x[k], Wb[(size_t)k * 8 + out], sum);
    } else {
      int c = out - 8;
      for (int k = lane; k < HID; k += 64) sum = fmaf(x[k], Wa[(size_t)k * 4 + c], sum);
    }
    sum = wave_sum(sum);
    if (lane == 0) {
      if (out < 8) {
        beta[(size_t)row * 8 + out] = 2.f / (1.f + expf(-sum));
      } else {
        int h = out - 8;
        float xx = sum + dt_bias[h];
        float sp = (xx > 20.f) ? xx : log1pf(expf(xx));
        g[(size_t)row * 4 + h] = -expf(A_log[h]) * sp;
      }
    }
  }
}

// ---------------- causal depthwise conv(K=4) + SiLU (+ optional l2norm over D)
// one block per (b,t,group); D threads; channel c = group*D + tid
template <int D, bool NORM>
__global__ __launch_bounds__(D) void conv_silu(const float* __restrict__ x,
                                               const float* __restrict__ w,
                                               float* __restrict__ y,
                                               int T, int C, int G, float eps) {
  int rb = blockIdx.x;
  int gi = rb % G;
  int bt = rb / G;
  int t = bt % T;
  int b = bt / T;
  int c = gi * D + threadIdx.x;
  const float* wc = w + (size_t)c * KSZ;
  float acc = 0.f;
#pragma unroll
  for (int i = 0; i < KSZ; i++) {
    int tt = t - (KSZ - 1) + i;
    if (tt >= 0) acc = fmaf(x[(size_t)(b * T + tt) * C + c], wc[i], acc);
  }
  float val = acc / (1.f + expf(-acc));  // SiLU
  if constexpr (NORM) {
    float ss = wave_sum(val * val);
    constexpr int NW = D / 64;
    __shared__ float sred[NW];
    if ((threadIdx.x & 63) == 0) sred[threadIdx.x >> 6] = ss;
    __syncthreads();
    float tot = 0.f;
#pragma unroll
    for (int i = 0; i < NW; i++) tot += sred[i];
    val *= rsqrtf(tot + eps);
  }
  y[(size_t)(b * T + t) * C + c] = val;
}

// ---------------- sequential gated-delta scan, one wave per (b,h,dv-column)
// state column s[DK] held as 2 floats/lane; three 64-lane dot-reductions per step
__global__ __launch_bounds__(256) void scan_kernel(const float* __restrict__ q,
                                                   const float* __restrict__ k,
                                                   const float* __restrict__ v,
                                                   const float* __restrict__ beta,
                                                   const float* __restrict__ g,
                                                   float* __restrict__ o,
                                                   int T) {
  const int wave = threadIdx.x >> 6, lane = threadIdx.x & 63;
  const int cb = blockIdx.x & 63;        // DV/4 = 64 column-blocks
  const int bh = blockIdx.x >> 6;        // b*H + h
  const int b = bh >> 2, h = bh & 3;     // H = 4
  const int col = cb * 4 + wave;
  const float2* q2 = (const float2*)q;
  const float2* k2 = (const float2*)k;
  float s0 = 0.f, s1 = 0.f;
  for (int t = 0; t < T; t++) {
    int bt = b * T + t;
    float decay = expf(g[(size_t)bt * H + h]);
    s0 *= decay;
    s1 *= decay;
#pragma unroll
    for (int i = 0; i < NH; i++) {
      int r = (bt * NH + i) * H + h;
      float2 kk = k2[(size_t)r * 64 + lane];
      float kv = wave_sum(kk.x * s0 + kk.y * s1);
      float coef = beta[r] * (v[(size_t)r * DV + col] - kv);
      s0 = fmaf(coef, kk.x, s0);
      s1 = fmaf(coef, kk.y, s1);
    }
    float2 qq = q2[(size_t)(bt * H + h) * 64 + lane];
    float ov = wave_sum(qq.x * s0 + qq.y * s1);
    if (lane == 0) o[(size_t)(bt * H + h) * DV + col] = ov;
  }
}

// ---------------- RMSNorm(o) * o_norm_weight * SiLU(gate), in place on o
__global__ __launch_bounds__(256) void post_norm_gate(float* __restrict__ o,
                                                      const float* __restrict__ gate,
                                                      const float* __restrict__ w) {
  int rb = blockIdx.x;  // (b*T+t)*H + h
  int tid = threadIdx.x;
  size_t base = (size_t)rb * 256 + tid;
  float ov = o[base];
  float ss = wave_sum(ov * ov);
  __shared__ float sred[4];
  if ((tid & 63) == 0) sred[tid >> 6] = ss;
  __syncthreads();
  float tot = sred[0] + sred[1] + sred[2] + sred[3];
  float rms = rsqrtf(tot * (1.f / 256.f) + 1e-5f);
  float gt = gate[base];
  o[base] = ov * rms * w[tid] * (gt / (1.f + expf(-gt)));
}

extern "C" void kernel_launch(void* const* d_in, const int* in_sizes, int n_in,
                              void* d_out, int out_size, void* d_ws, size_t ws_size,
                              hipStream_t stream) {
  const float* hs      = (const float*)d_in[0];
  const float* Wq      = (const float*)d_in[1];
  const float* Wk      = (const float*)d_in[2];
  const float* Wv      = (const float*)d_in[3];
  const float* Wb      = (const float*)d_in[4];
  const float* Wa      = (const float*)d_in[5];
  const float* Wg      = (const float*)d_in[6];
  const float* Wo      = (const float*)d_in[7];
  const float* A_log   = (const float*)d_in[8];
  const float* dt_bias = (const float*)d_in[9];
  const float* wq_conv = (const float*)d_in[10];
  const float* wk_conv = (const float*)d_in[11];
  const float* wv_conv = (const float*)d_in[12];
  const float* o_w     = (const float*)d_in[13];
  float* out = (float*)d_out;

  const int B = 2, T = 1024, M = B * T;  // M = 2048 rows

  // workspace layout (fp32), ~60 MiB total
  float* ws    = (float*)d_ws;
  float* q_pre = ws;                      // M*512
  float* k_pre = q_pre + (size_t)M * 512; // M*1024
  float* v_pre = k_pre + (size_t)M * 1024;// M*2048
  float* gateb = v_pre + (size_t)M * 2048;// M*1024
  float* kbuf  = gateb + (size_t)M * 1024;// M*1024
  float* vbuf  = kbuf + (size_t)M * 1024; // M*2048
  float* betab = vbuf + (size_t)M * 2048; // M*8
  float* gb    = betab + (size_t)M * 8;   // M*4
  float* qbuf  = out;    // scratch in d_out (M*512 <= out_size), fully overwritten by final GEMM
  float* obuf  = v_pre;  // reuse: v_pre dead after conv_v

  dim3 blk(256);
  // big projections
  gemm_f32<<<dim3(512 / GT, M / GT), blk, 0, stream>>>(hs, Wq, q_pre, M, 512, HID);
  gemm_f32<<<dim3(1024 / GT, M / GT), blk, 0, stream>>>(hs, Wk, k_pre, M, 1024, HID);
  gemm_f32<<<dim3(2048 / GT, M / GT), blk, 0, stream>>>(hs, Wv, v_pre, M, 2048, HID);
  gemm_f32<<<dim3(1024 / GT, M / GT), blk, 0, stream>>>(hs, Wg, gateb, M, 1024, HID);
  // beta / g with fused activations
  proj_bg<<<M, 256, 0, stream>>>(hs, Wb, Wa, A_log, dt_bias, betab, gb);
  // conv + SiLU (+ l2norm for q,k)
  conv_silu<128, true><<<M * 4, 128, 0, stream>>>(q_pre, wq_conv, qbuf, T, 512, 4, 1e-6f);
  conv_silu<128, true><<<M * 8, 128, 0, stream>>>(k_pre, wk_conv, kbuf, T, 1024, 8, 1e-6f);
  conv_silu<256, false><<<M * 8, 256, 0, stream>>>(v_pre, wv_conv, vbuf, T, 2048, 8, 1e-6f);
  // sequential scan: grid = B*H * (DV/4) = 512 blocks
  scan_kernel<<<512, 256, 0, stream>>>(qbuf, kbuf, vbuf, betab, gb, obuf, T);
  // epilogue norm/gate
  post_norm_gate<<<M * H, 256, 0, stream>>>(obuf, gateb, o_w);
  // output projection
  gemm_f32<<<dim3(1024 / GT, M / GT), blk, 0, stream>>>(obuf, Wo, out, M, HID, HID);
}

// Round 2
// 996.832 us; speedup vs baseline: 1.6273x; 1.6273x over previous
//
#include <hip/hip_runtime.h>
#include <cstdint>
#include <cstddef>

#define H 4
#define DK 128
#define DV 256
#define NH 2
#define HID 1024
#define KSZ 4
#define NTOT 4608  // packed projection width: 512 q | 1024 k | 2048 v | 1024 g

__device__ __forceinline__ float wave_sum(float x) {
#pragma unroll
  for (int off = 1; off < 64; off <<= 1) x += __shfl_xor(x, off, 64);
  return x;
}

// full-wave64 sum via DPP (VALU-latency), result broadcast via readlane(63)
__device__ __forceinline__ float dpp_sum(float x) {
  x += __int_as_float(__builtin_amdgcn_update_dpp(0, __float_as_int(x), 0x111, 0xf, 0xf, true)); // row_shr:1
  x += __int_as_float(__builtin_amdgcn_update_dpp(0, __float_as_int(x), 0x112, 0xf, 0xf, true)); // row_shr:2
  x += __int_as_float(__builtin_amdgcn_update_dpp(0, __float_as_int(x), 0x114, 0xf, 0xf, true)); // row_shr:4
  x += __int_as_float(__builtin_amdgcn_update_dpp(0, __float_as_int(x), 0x118, 0xf, 0xf, true)); // row_shr:8
  x += __int_as_float(__builtin_amdgcn_update_dpp(0, __float_as_int(x), 0x142, 0xf, 0xf, true)); // row_bcast:15
  x += __int_as_float(__builtin_amdgcn_update_dpp(0, __float_as_int(x), 0x143, 0xf, 0xf, true)); // row_bcast:31
  return __int_as_float(__builtin_amdgcn_readlane(__float_as_int(x), 63));
}

// ---------------- fused qkvg projection GEMM: C[M,4608] = hs[M,1024] @ [Wq|Wk|Wv|Wg]
#define BM 128
#define BN 128
#define BK 16
#define LDT 132
__global__ __launch_bounds__(256) void gemm_qkvg(const float* __restrict__ A,
                                                 const float* __restrict__ Wq,
                                                 const float* __restrict__ Wk,
                                                 const float* __restrict__ Wv,
                                                 const float* __restrict__ Wg) {
  __shared__ float As[BK][LDT];
  __shared__ float Bs[BK][LDT];
  const int tid = threadIdx.x;
  const int tx = tid & 15, ty = tid >> 4;
  const int row0 = blockIdx.y * BM;
  const int col0 = blockIdx.x * BN;
  const float* Bsel;
  int ldb, bcol;
  if (col0 < 512)       { Bsel = Wq; ldb = 512;  bcol = col0; }
  else if (col0 < 1536) { Bsel = Wk; ldb = 1024; bcol = col0 - 512; }
  else if (col0 < 3584) { Bsel = Wv; ldb = 2048; bcol = col0 - 1536; }
  else                  { Bsel = Wg; ldb = 1024; bcol = col0 - 3584; }
  float* C = (float*)Wq;  // unused; real C passed via A? -- replaced below
  (void)C;
  extern __shared__ float dummy_unused[];  // (not used; static LDS above)
  float acc[2][2][4][4] = {};
  const int K = HID;
  // C pointer passed through global symbol-free route: see launch (we pass C as A offset trick is
  // avoided -- C is an explicit parameter in the real signature below). This kernel body is inlined
  // via the wrapper below.
  // (placeholder removed)
  for (int k0 = 0; k0 < K; k0 += BK) {
#pragma unroll
    for (int i = 0; i < 2; i++) {
      int f = tid + i * 256;
      int row = f >> 2, kq = (f & 3) * 4;
      float4 av = *(const float4*)&A[(size_t)(row0 + row) * K + k0 + kq];
      As[kq + 0][row] = av.x;
      As[kq + 1][row] = av.y;
      As[kq + 2][row] = av.z;
      As[kq + 3][row] = av.w;
      int kk = f >> 5, cq = (f & 31) * 4;
      *(float4*)&Bs[kk][cq] = *(const float4*)&Bsel[(size_t)(k0 + kk) * ldb + bcol + cq];
    }
    __syncthreads();
#pragma unroll
    for (int kk = 0; kk < BK; kk++) {
      float4 a0 = *(const float4*)&As[kk][ty * 4];
      float4 a1 = *(const float4*)&As[kk][64 + ty * 4];
      float4 b0 = *(const float4*)&Bs[kk][tx * 4];
      float4 b1 = *(const float4*)&Bs[kk][64 + tx * 4];
      float ar[2][4] = {{a0.x, a0.y, a0.z, a0.w}, {a1.x, a1.y, a1.z, a1.w}};
      float br[2][4] = {{b0.x, b0.y, b0.z, b0.w}, {b1.x, b1.y, b1.z, b1.w}};
#pragma unroll
      for (int ri = 0; ri < 2; ri++)
#pragma unroll
        for (int ci = 0; ci < 2; ci++)
#pragma unroll
          for (int i = 0; i < 4; i++)
#pragma unroll
            for (int j = 0; j < 4; j++)
              acc[ri][ci][i][j] = fmaf(ar[ri][i], br[ci][j], acc[ri][ci][i][j]);
    }
    __syncthreads();
  }
  // store handled by caller-visible global C -- see real kernel below
}

// Real fused kernel (with C param). The above was a sketch; this is the one actually launched.
__global__ __launch_bounds__(256) void gemm_qkvg_c(const float* __restrict__ A,
                                                   const float* __restrict__ Wq,
                                                   const float* __restrict__ Wk,
                                                   const float* __restrict__ Wv,
                                                   const float* __restrict__ Wg,
                                                   float* __restrict__ C) {
  __shared__ float As[BK][LDT];
  __shared__ float Bs[BK][LDT];
  const int tid = threadIdx.x;
  const int tx = tid & 15, ty = tid >> 4;
  const int row0 = blockIdx.y * BM;
  const int col0 = blockIdx.x * BN;
  const float* Bsel;
  int ldb, bcol;
  if (col0 < 512)       { Bsel = Wq; ldb = 512;  bcol = col0; }
  else if (col0 < 1536) { Bsel = Wk; ldb = 1024; bcol = col0 - 512; }
  else if (col0 < 3584) { Bsel = Wv; ldb = 2048; bcol = col0 - 1536; }
  else                  { Bsel = Wg; ldb = 1024; bcol = col0 - 3584; }
  float acc[2][2][4][4] = {};
  const int K = HID;
  for (int k0 = 0; k0 < K; k0 += BK) {
#pragma unroll
    for (int i = 0; i < 2; i++) {
      int f = tid + i * 256;
      int row = f >> 2, kq = (f & 3) * 4;
      float4 av = *(const float4*)&A[(size_t)(row0 + row) * K + k0 + kq];
      As[kq + 0][row] = av.x;
      As[kq + 1][row] = av.y;
      As[kq + 2][row] = av.z;
      As[kq + 3][row] = av.w;
      int kk = f >> 5, cq = (f & 31) * 4;
      *(float4*)&Bs[kk][cq] = *(const float4*)&Bsel[(size_t)(k0 + kk) * ldb + bcol + cq];
    }
    __syncthreads();
#pragma unroll
    for (int kk = 0; kk < BK; kk++) {
      float4 a0 = *(const float4*)&As[kk][ty * 4];
      float4 a1 = *(const float4*)&As[kk][64 + ty * 4];
      float4 b0 = *(const float4*)&Bs[kk][tx * 4];
      float4 b1 = *(const float4*)&Bs[kk][64 + tx * 4];
      float ar[2][4] = {{a0.x, a0.y, a0.z, a0.w}, {a1.x, a1.y, a1.z, a1.w}};
      float br[2][4] = {{b0.x, b0.y, b0.z, b0.w}, {b1.x, b1.y, b1.z, b1.w}};
#pragma unroll
      for (int ri = 0; ri < 2; ri++)
#pragma unroll
        for (int ci = 0; ci < 2; ci++)
#pragma unroll
          for (int i = 0; i < 4; i++)
#pragma unroll
            for (int j = 0; j < 4; j++)
              acc[ri][ci][i][j] = fmaf(ar[ri][i], br[ci][j], acc[ri][ci][i][j]);
    }
    __syncthreads();
  }
#pragma unroll
  for (int ri = 0; ri < 2; ri++)
#pragma unroll
    for (int i = 0; i < 4; i++) {
      size_t r = (size_t)(row0 + ri * 64 + ty * 4 + i);
#pragma unroll
      for (int ci = 0; ci < 2; ci++) {
        float4 o4 = {acc[ri][ci][i][0], acc[ri][ci][i][1], acc[ri][ci][i][2], acc[ri][ci][i][3]};
        *(float4*)&C[r * NTOT + col0 + ci * 64 + tx * 4] = o4;
      }
    }
}

// ---------------- generic 128x128 fp32 GEMM (for output projection); lda for strided A
__global__ __launch_bounds__(256) void gemm128(const float* __restrict__ A, int lda,
                                               const float* __restrict__ B, int ldb,
                                               float* __restrict__ C, int ldc, int K) {
  __shared__ float As[BK][LDT];
  __shared__ float Bs[BK][LDT];
  const int tid = threadIdx.x;
  const int tx = tid & 15, ty = tid >> 4;
  const int row0 = blockIdx.y * BM;
  const int col0 = blockIdx.x * BN;
  float acc[2][2][4][4] = {};
  for (int k0 = 0; k0 < K; k0 += BK) {
#pragma unroll
    for (int i = 0; i < 2; i++) {
      int f = tid + i * 256;
      int row = f >> 2, kq = (f & 3) * 4;
      float4 av = *(const float4*)&A[(size_t)(row0 + row) * lda + k0 + kq];
      As[kq + 0][row] = av.x;
      As[kq + 1][row] = av.y;
      As[kq + 2][row] = av.z;
      As[kq + 3][row] = av.w;
      int kk = f >> 5, cq = (f & 31) * 4;
      *(float4*)&Bs[kk][cq] = *(const float4*)&B[(size_t)(k0 + kk) * ldb + col0 + cq];
    }
    __syncthreads();
#pragma unroll
    for (int kk = 0; kk < BK; kk++) {
      float4 a0 = *(const float4*)&As[kk][ty * 4];
      float4 a1 = *(const float4*)&As[kk][64 + ty * 4];
      float4 b0 = *(const float4*)&Bs[kk][tx * 4];
      float4 b1 = *(const float4*)&Bs[kk][64 + tx * 4];
      float ar[2][4] = {{a0.x, a0.y, a0.z, a0.w}, {a1.x, a1.y, a1.z, a1.w}};
      float br[2][4] = {{b0.x, b0.y, b0.z, b0.w}, {b1.x, b1.y, b1.z, b1.w}};
#pragma unroll
      for (int ri = 0; ri < 2; ri++)
#pragma unroll
        for (int ci = 0; ci < 2; ci++)
#pragma unroll
          for (int i = 0; i < 4; i++)
#pragma unroll
            for (int j = 0; j < 4; j++)
              acc[ri][ci][i][j] = fmaf(ar[ri][i], br[ci][j], acc[ri][ci][i][j]);
    }
    __syncthreads();
  }
#pragma unroll
  for (int ri = 0; ri < 2; ri++)
#pragma unroll
    for (int i = 0; i < 4; i++) {
      size_t r = (size_t)(row0 + ri * 64 + ty * 4 + i);
#pragma unroll
      for (int ci = 0; ci < 2; ci++) {
        float4 o4 = {acc[ri][ci][i][0], acc[ri][ci][i][1], acc[ri][ci][i][2], acc[ri][ci][i][3]};
        *(float4*)&C[r * ldc + col0 + ci * 64 + tx * 4] = o4;
      }
    }
}

// ---------------- beta / g tiny projections with fused activations
__global__ __launch_bounds__(256) void proj_bg(const float* __restrict__ hs,
                                               const float* __restrict__ Wb,
                                               const float* __restrict__ Wa,
                                               const float* __restrict__ A_log,
                                               const float* __restrict__ dt_bias,
                                               float* __restrict__ beta,
                                               float* __restrict__ g) {
  int row = blockIdx.x;
  int lane = threadIdx.x & 63;
  int wave = threadIdx.x >> 6;
  const float* x = hs + (size_t)row * HID;
  for (int out = wave; out < 12; out += 4) {
    float sum = 0.f;
    if (out < 8) {
      for (int k = lane; k < HID; k += 64) sum = fmaf(x[k], Wb[(size_t)k * 8 + out], sum);
    } else {
      int c = out - 8;
      for (int k = lane; k < HID; k += 64) sum = fmaf(x[k], Wa[(size_t)k * 4 + c], sum);
    }
    sum = wave_sum(sum);
    if (lane == 0) {
      if (out < 8) {
        beta[(size_t)row * 8 + out] = 2.f / (1.f + expf(-sum));
      } else {
        int h = out - 8;
        float xx = sum + dt_bias[h];
        float sp = (xx > 20.f) ? xx : log1pf(expf(xx));
        g[(size_t)row * 4 + h] = -expf(A_log[h]) * sp;
      }
    }
  }
}

// ---------------- causal depthwise conv(K=4) + SiLU (+ optional l2norm over D)
// x is the packed projection buffer at this projection's base column; ldx = packed row stride
template <int D, bool NORM>
__global__ __launch_bounds__(D) void conv_silu(const float* __restrict__ x, int ldx,
                                               const float* __restrict__ w,
                                               float* __restrict__ y,
                                               int T, int C, int G, float eps) {
  int rb = blockIdx.x;
  int gi = rb % G;
  int bt = rb / G;
  int t = bt % T;
  int b = bt / T;
  int c = gi * D + threadIdx.x;
  const float* wc = w + (size_t)c * KSZ;
  float acc = 0.f;
#pragma unroll
  for (int i = 0; i < KSZ; i++) {
    int tt = t - (KSZ - 1) + i;
    if (tt >= 0) acc = fmaf(x[(size_t)(b * T + tt) * ldx + c], wc[i], acc);
  }
  float val = acc / (1.f + expf(-acc));
  if constexpr (NORM) {
    float ss = wave_sum(val * val);
    constexpr int NW = D / 64;
    __shared__ float sred[NW];
    if ((threadIdx.x & 63) == 0) sred[threadIdx.x >> 6] = ss;
    __syncthreads();
    float tot = 0.f;
#pragma unroll
    for (int i = 0; i < NW; i++) tot += sred[i];
    val *= rsqrtf(tot + eps);
  }
  y[(size_t)(b * T + t) * C + c] = val;
}

// ---------------- sequential gated-delta scan, one wave per (b,h,dv-column)
// DPP-based reductions; o written strided into packed buffer (ld = NTOT) at col h*256+col
__global__ __launch_bounds__(256) void scan_kernel(const float* __restrict__ q,
                                                   const float* __restrict__ k,
                                                   const float* __restrict__ v,
                                                   const float* __restrict__ beta,
                                                   const float* __restrict__ g,
                                                   float* __restrict__ o,
                                                   int T) {
  const int wave = threadIdx.x >> 6, lane = threadIdx.x & 63;
  const int cb = blockIdx.x & 63;
  const int bh = blockIdx.x >> 6;
  const int b = bh >> 2, h = bh & 3;
  const int col = cb * 4 + wave;
  const float2* q2 = (const float2*)q;
  const float2* k2 = (const float2*)k;
  float s0 = 0.f, s1 = 0.f;

  int bt0 = b * T;
  float2 ka = k2[((size_t)(bt0 * NH + 0) * H + h) * 64 + lane];
  float2 kb = k2[((size_t)(bt0 * NH + 1) * H + h) * 64 + lane];
  float va = v[((size_t)(bt0 * NH + 0) * H + h) * DV + col];
  float vb = v[((size_t)(bt0 * NH + 1) * H + h) * DV + col];
  float2 qq = q2[((size_t)(bt0 * H + h)) * 64 + lane];
  float bea = beta[(size_t)(bt0 * NH + 0) * H + h];
  float beb = beta[(size_t)(bt0 * NH + 1) * H + h];
  float gg = g[(size_t)bt0 * H + h];

  for (int t = 0; t < T; t++) {
    // prefetch next step (clamped)
    int tn = (t + 1 < T) ? t + 1 : t;
    int btn = b * T + tn;
    float2 kan = k2[((size_t)(btn * NH + 0) * H + h) * 64 + lane];
    float2 kbn = k2[((size_t)(btn * NH + 1) * H + h) * 64 + lane];
    float van = v[((size_t)(btn * NH + 0) * H + h) * DV + col];
    float vbn = v[((size_t)(btn * NH + 1) * H + h) * DV + col];
    float2 qqn = q2[((size_t)(btn * H + h)) * 64 + lane];
    float bean = beta[(size_t)(btn * NH + 0) * H + h];
    float bebn = beta[(size_t)(btn * NH + 1) * H + h];
    float ggn = g[(size_t)btn * H + h];

    float decay = __expf(gg);
    s0 *= decay;
    s1 *= decay;
    // head copy 0
    float kv = dpp_sum(ka.x * s0 + ka.y * s1);
    float coef = bea * (va - kv);
    s0 = fmaf(coef, ka.x, s0);
    s1 = fmaf(coef, ka.y, s1);
    // head copy 1
    kv = dpp_sum(kb.x * s0 + kb.y * s1);
    coef = beb * (vb - kv);
    s0 = fmaf(coef, kb.x, s0);
    s1 = fmaf(coef, kb.y, s1);
    // output
    float ov = dpp_sum(qq.x * s0 + qq.y * s1);
    if (lane == 0) o[(size_t)(b * T + t) * NTOT + h * 256 + col] = ov;

    ka = kan; kb = kbn; va = van; vb = vbn; qq = qqn;
    bea = bean; beb = bebn; gg = ggn;
  }
}

// ---------------- RMSNorm(o) * w * SiLU(gate); o and gate strided in packed buffer
__global__ __launch_bounds__(256) void post_norm_gate(float* __restrict__ o,
                                                      const float* __restrict__ gate,
                                                      const float* __restrict__ w) {
  int rb = blockIdx.x;  // bt*H + h
  int bt = rb >> 2, h = rb & 3;
  int tid = threadIdx.x;
  size_t ob = (size_t)bt * NTOT + h * 256 + tid;
  float ov = o[ob];
  float ss = wave_sum(ov * ov);
  __shared__ float sred[4];
  if ((tid & 63) == 0) sred[tid >> 6] = ss;
  __syncthreads();
  float tot = sred[0] + sred[1] + sred[2] + sred[3];
  float rms = rsqrtf(tot * (1.f / 256.f) + 1e-5f);
  float gt = gate[(size_t)bt * NTOT + h * 256 + tid];
  o[ob] = ov * rms * w[tid] * (gt / (1.f + expf(-gt)));
}

extern "C" void kernel_launch(void* const* d_in, const int* in_sizes, int n_in,
                              void* d_out, int out_size, void* d_ws, size_t ws_size,
                              hipStream_t stream) {
  const float* hs      = (const float*)d_in[0];
  const float* Wq      = (const float*)d_in[1];
  const float* Wk      = (const float*)d_in[2];
  const float* Wv      = (const float*)d_in[3];
  const float* Wb      = (const float*)d_in[4];
  const float* Wa      = (const float*)d_in[5];
  const float* Wg      = (const float*)d_in[6];
  const float* Wo      = (const float*)d_in[7];
  const float* A_log   = (const float*)d_in[8];
  const float* dt_bias = (const float*)d_in[9];
  const float* wq_conv = (const float*)d_in[10];
  const float* wk_conv = (const float*)d_in[11];
  const float* wv_conv = (const float*)d_in[12];
  const float* o_w     = (const float*)d_in[13];
  float* out = (float*)d_out;

  const int B = 2, T = 1024, M = B * T;

  float* ws    = (float*)d_ws;
  float* qkvg  = ws;                          // M*4608 packed projections; later reused for o (cols 0..1023) while gate (cols 3584+) stays live
  float* kbuf  = qkvg + (size_t)M * NTOT;     // M*1024
  float* vbuf  = kbuf + (size_t)M * 1024;     // M*2048
  float* betab = vbuf + (size_t)M * 2048;     // M*8
  float* gb    = betab + (size_t)M * 8;       // M*4
  float* qbuf  = out;                         // M*512 scratch in d_out; fully overwritten by final GEMM

  // fused projections -> packed [M,4608]
  gemm_qkvg_c<<<dim3(NTOT / BN, M / BM), 256, 0, stream>>>(hs, Wq, Wk, Wv, Wg, qkvg);
  // beta / g
  proj_bg<<<M, 256, 0, stream>>>(hs, Wb, Wa, A_log, dt_bias, betab, gb);
  // conv + SiLU (+ l2norm for q,k) from packed buffer into dense buffers
  conv_silu<128, true><<<M * 4, 128, 0, stream>>>(qkvg + 0, NTOT, wq_conv, qbuf, T, 512, 4, 1e-6f);
  conv_silu<128, true><<<M * 8, 128, 0, stream>>>(qkvg + 512, NTOT, wk_conv, kbuf, T, 1024, 8, 1e-6f);
  conv_silu<256, false><<<M * 8, 256, 0, stream>>>(qkvg + 1536, NTOT, wv_conv, vbuf, T, 2048, 8, 1e-6f);
  // scan: o written strided into qkvg cols 0..1023 (dead after convs)
  scan_kernel<<<512, 256, 0, stream>>>(qbuf, kbuf, vbuf, betab, gb, qkvg, T);
  // epilogue norm/gate (gate = qkvg cols 3584..4607)
  post_norm_gate<<<M * H, 256, 0, stream>>>(qkvg, qkvg + 3584, o_w);
  // output projection: A = o strided in qkvg (lda = 4608)
  gemm128<<<dim3(HID / BN, M / BM), 256, 0, stream>>>(qkvg, NTOT, Wo, HID, out, HID, HID);
}